// Round 16
// baseline (149.234 us; speedup 1.0000x reference)
//
#include <hip/hip_runtime.h>
#include <hip/hip_bf16.h>

typedef __hip_bfloat16 bf16;
typedef __attribute__((ext_vector_type(4))) float f32x4;
typedef __attribute__((ext_vector_type(8))) __bf16 bf16x8;

#define T_TOK 1024
#define HDIM 1024
#define FDIM 4096
#define NEXP 8
#define RLORA 16
#define LSCALE 2.0f
#define N1 8448   // cols of fused GEMM1: 4096 gate + 4096 up + 256 XA
#define N2 1152   // cols of fused GEMM2: 1024 down + 128 AD
#define SPLITK2 4
#define ACT_NCHUNK 8

__device__ inline float b2f(bf16 v) { return __bfloat162float(v); }
__device__ inline bf16 f2b(float v) { return __float2bfloat16(v); }
__device__ inline ushort f2u(float v) { return __builtin_bit_cast(ushort, __float2bfloat16(v)); }
__device__ inline float u2f(ushort v) { return __bfloat162float(__builtin_bit_cast(bf16, v)); }
__device__ inline float lo2f(unsigned w) { return __builtin_bit_cast(float, w << 16); }
__device__ inline float hi2f(unsigned w) { return __builtin_bit_cast(float, w & 0xffff0000u); }

typedef const __attribute__((address_space(1))) unsigned int* gptr_t;
typedef __attribute__((address_space(3))) unsigned int* lptr_t;
__device__ __forceinline__ void glds16(const void* g, void* l) {
    __builtin_amdgcn_global_load_lds((gptr_t)g, (lptr_t)l, 16, 0, 0);
}

// ---------------- Router: logits, softmax, top2 -----------------------------
__global__ __launch_bounds__(256) void router_kernel(
    const float* __restrict__ x, const float* __restrict__ noise,
    const float* __restrict__ w_route, const float* __restrict__ w_noise,
    float* __restrict__ rl_out, int* __restrict__ SEL, float* __restrict__ WTS)
{
    const int t = blockIdx.x, tid = threadIdx.x;
    const float* xr = x + t * HDIM;
    float acc[16];
#pragma unroll
    for (int j = 0; j < 16; j++) acc[j] = 0.f;
    for (int h = tid; h < HDIM; h += 256) {
        float xv = xr[h];
        const float* wr = w_route + h * NEXP;
        const float* wn = w_noise + h * NEXP;
#pragma unroll
        for (int j = 0; j < 8; j++) acc[j] += xv * wr[j];
#pragma unroll
        for (int j = 0; j < 8; j++) acc[8 + j] += xv * wn[j];
    }
#pragma unroll
    for (int j = 0; j < 16; j++) {
        for (int off = 32; off > 0; off >>= 1) acc[j] += __shfl_down(acc[j], off, 64);
    }
    __shared__ float red[4][16];
    const int wave = tid >> 6, lane = tid & 63;
    if (lane == 0) {
#pragma unroll
        for (int j = 0; j < 16; j++) red[wave][j] = acc[j];
    }
    __syncthreads();
    if (tid == 0) {
        float rl[8];
#pragma unroll
        for (int j = 0; j < 8; j++) {
            float lg = red[0][j] + red[1][j] + red[2][j] + red[3][j];
            float nl = red[0][8 + j] + red[1][8 + j] + red[2][8 + j] + red[3][8 + j];
            float sp = fmaxf(nl, 0.f) + log1pf(expf(-fabsf(nl)));
            rl[j] = lg + noise[t * NEXP + j] * sp;
            rl_out[t * NEXP + j] = rl[j];
        }
        float m = rl[0];
#pragma unroll
        for (int j = 1; j < 8; j++) m = fmaxf(m, rl[j]);
        float p[8];
#pragma unroll
        for (int j = 0; j < 8; j++) p[j] = expf(rl[j] - m);
        int i1 = 0;
#pragma unroll
        for (int j = 1; j < 8; j++) if (p[j] > p[i1]) i1 = j;
        int i2 = (i1 == 0) ? 1 : 0;
#pragma unroll
        for (int j = 0; j < 8; j++) { if (j != i1 && p[j] > p[i2]) i2 = j; }
        float w1 = p[i1] / (p[i1] + p[i2]);
        float w2 = p[i2] / (p[i1] + p[i2]);
        SEL[t * 2 + 0] = i1; SEL[t * 2 + 1] = i2;
        WTS[t * 2 + 0] = w1; WTS[t * 2 + 1] = w2;
    }
}

// ---------------- Fused prep: transposes + LoRA packs + x convert + lists ---
__device__ __forceinline__ void transpose_tile(
    const float* __restrict__ in, ushort* __restrict__ out,
    int rows, int cols, int bx, int by, int tid)
{
    __shared__ float tile[32][33];
    const int tx = tid & 31, ty = tid >> 5;
#pragma unroll
    for (int i = 0; i < 32; i += 8)
        tile[ty + i][tx] = in[(size_t)(by + ty + i) * cols + bx + tx];
    __syncthreads();
#pragma unroll
    for (int i = 0; i < 32; i += 8)
        out[(size_t)(bx + ty + i) * rows + by + tx] = f2u(tile[tx][ty + i]);
}

__global__ __launch_bounds__(256) void prep_kernel(
    const float* __restrict__ x,
    const float* __restrict__ w_gate, const float* __restrict__ w_up,
    const float* __restrict__ w_down,
    const float* __restrict__ a_gate, const float* __restrict__ a_up,
    const float* __restrict__ a_down,
    ushort* __restrict__ XB, ushort* __restrict__ WGUA, ushort* __restrict__ WDA,
    const int* __restrict__ SEL, int* __restrict__ CNT, int* __restrict__ LIST)
{
    const int bid = blockIdx.x, tid = threadIdx.x;
    if (bid < 4096) {
        transpose_tile(w_gate, WGUA, HDIM, FDIM, (bid & 127) * 32, (bid >> 7) * 32, tid);
    } else if (bid < 8192) {
        const int s = bid - 4096;
        transpose_tile(w_up, WGUA + (size_t)4096 * HDIM, HDIM, FDIM, (s & 127) * 32, (s >> 7) * 32, tid);
    } else if (bid < 12288) {
        const int s = bid - 8192;
        transpose_tile(w_down, WDA, FDIM, HDIM, (s & 31) * 32, (s >> 5) * 32, tid);
    } else if (bid < 12544) {
        const int row = bid - 12288;  // 0..255: e*32 + mat*16 + r
        const int e = row >> 5, mat = (row >> 4) & 1, r = row & 15;
        const float* src = (mat ? a_up : a_gate) + (size_t)e * HDIM * RLORA;
        ushort* dst = WGUA + (size_t)(8192 + row) * HDIM;
        for (int h = tid; h < HDIM; h += 256) dst[h] = f2u(src[h * RLORA + r]);
    } else if (bid < 12672) {
        const int row = bid - 12544;  // 0..127: e*16 + r
        const int e = row >> 4, r = row & 15;
        const float* src = a_down + (size_t)e * FDIM * RLORA;
        ushort* dst = WDA + (size_t)(1024 + row) * FDIM;
        for (int f = tid; f < FDIM; f += 256) dst[f] = f2u(src[f * RLORA + r]);
    } else if (bid < 13696) {
        const int i = (bid - 12672) * 256 + tid;
        const float4 v = *reinterpret_cast<const float4*>(x + (size_t)i * 4);
        ushort4 o;
        o.x = f2u(v.x); o.y = f2u(v.y); o.z = f2u(v.z); o.w = f2u(v.w);
        *reinterpret_cast<ushort4*>(XB + (size_t)i * 4) = o;
    } else {
        // expert list build (single block, LDS counters — no global memset)
        __shared__ int cnt[NEXP];
        if (tid < NEXP) cnt[tid] = 0;
        __syncthreads();
        for (int p = tid; p < 2 * T_TOK; p += 256) {
            const int e = SEL[p];
            const int idx = atomicAdd(&cnt[e], 1);
            LIST[e * 2048 + idx] = p;
        }
        __syncthreads();
        if (tid < NEXP) CNT[tid] = cnt[tid];
    }
}

// ---- MFMA GEMM: 128x128, BK=128 per phase (2 x 64 tiles), glds + swizzle ---
// Verified-safe sync invariant: ALL stages -> __syncthreads (full vmcnt+lgkm
// drain) -> ALL computes -> __syncthreads. Two K-tiles staged per phase to
// amortize the fixed ~2.7k-cycle phase latency over 2x the MFMA work.
template <int SPLITK>
__global__ __launch_bounds__(256) void gemm128(
    const ushort* __restrict__ A, const ushort* __restrict__ Bt,
    ushort* __restrict__ C, int M, int N, int Kd, int ny)
{
    __shared__ __align__(16) ushort sA[2][128 * 64];
    __shared__ __align__(16) ushort sB[2][128 * 64];
    const int nwg = gridDim.x;
    const int q = nwg >> 3;  // nwg % 8 == 0 required
    const int wg = (blockIdx.x & 7) * q + (blockIdx.x >> 3);
    const int bn0 = (wg / ny) * 128, bm0 = (wg % ny) * 128;

    const int tid = threadIdx.x;
    const int wave = tid >> 6, lane = tid & 63;
    const int wm = wave >> 1, wn = wave & 1;

    f32x4 acc[4][4];
#pragma unroll
    for (int m = 0; m < 4; m++)
#pragma unroll
        for (int n = 0; n < 4; n++) acc[m][n] = (f32x4){0.f, 0.f, 0.f, 0.f};

    const int srow = tid >> 3;                       // 0..31 per pass
    const int sgrp8 = ((tid & 7) ^ (srow & 7)) * 8;  // pre-swizzled col (elems)

    const int kchunk = Kd / SPLITK;
    const int kbeg = blockIdx.z * kchunk, kend = kbeg + kchunk;

    for (int k0 = kbeg; k0 < kend; k0 += 128) {
        // stage BOTH 64-wide K-tiles of this 128-wide phase
#pragma unroll
        for (int b = 0; b < 2; b++) {
            const int kk = k0 + b * 64;
#pragma unroll
            for (int i = 0; i < 4; i++) {
                const int row = i * 32 + srow;
                glds16(A + (size_t)(bm0 + row) * Kd + kk + sgrp8, &sA[b][i * 2048 + wave * 512]);
                glds16(Bt + (size_t)(bn0 + row) * Kd + kk + sgrp8, &sB[b][i * 2048 + wave * 512]);
            }
        }
        __syncthreads();  // full drain: both tiles resident (verified-safe)
#pragma unroll
        for (int b = 0; b < 2; b++) {
#pragma unroll
            for (int kk = 0; kk < 2; kk++) {
                bf16x8 af[4], bfr[4];
                const int colb = (kk * 32 + (lane >> 4) * 8) * 2;
#pragma unroll
                for (int m = 0; m < 4; m++) {
                    const int row = wm * 64 + m * 16 + (lane & 15);
                    af[m] = *reinterpret_cast<const bf16x8*>(
                        (const char*)sA[b] + row * 128 + (colb ^ ((row & 7) << 4)));
                }
#pragma unroll
                for (int n = 0; n < 4; n++) {
                    const int row = wn * 64 + n * 16 + (lane & 15);
                    bfr[n] = *reinterpret_cast<const bf16x8*>(
                        (const char*)sB[b] + row * 128 + (colb ^ ((row & 7) << 4)));
                }
#pragma unroll
                for (int m = 0; m < 4; m++)
#pragma unroll
                    for (int n = 0; n < 4; n++)
                        acc[m][n] = __builtin_amdgcn_mfma_f32_16x16x32_bf16(af[m], bfr[n], acc[m][n], 0, 0, 0);
            }
        }
        __syncthreads();  // all reads done before next phase overwrites
    }

    const size_t zoff = (size_t)blockIdx.z * M * N;
    const int rg = lane & 15, qg = lane >> 4;
#pragma unroll
    for (int m = 0; m < 4; m++) {
#pragma unroll
        for (int n = 0; n < 4; n++) {
            const int row0 = bm0 + wm * 64 + m * 16 + qg * 4;
            const int col = bn0 + wn * 64 + n * 16 + rg;
#pragma unroll
            for (int j = 0; j < 4; j++)
                C[zoff + (size_t)(row0 + j) * N + col] = f2u(acc[m][n][j]);
        }
    }
}

// -------- Expert-grouped LoRA gate/up + SiLU -> ACT, B in registers ---------
__global__ __launch_bounds__(256) void act3_kernel(
    const ushort* __restrict__ GU,   // [T, N1] bf16: G | U | XA
    const float* __restrict__ b_gate, const float* __restrict__ b_up,
    const int* __restrict__ CNT, const int* __restrict__ LIST,
    unsigned* __restrict__ ACT)      // [2048, FDIM/2] packed 2xbf16
{
    const int e = blockIdx.x, chunk = blockIdx.z;
    const int tid = threadIdx.x;
    const int f = blockIdx.y * 512 + tid * 2;

    float2 bg[16], bu[16];
    {
        const float* bgp = b_gate + (size_t)e * RLORA * FDIM + f;
        const float* bup = b_up + (size_t)e * RLORA * FDIM + f;
#pragma unroll
        for (int r = 0; r < 16; r++) {
            bg[r] = *reinterpret_cast<const float2*>(bgp + (size_t)r * FDIM);
            bu[r] = *reinterpret_cast<const float2*>(bup + (size_t)r * FDIM);
        }
    }

    const int n = __builtin_amdgcn_readfirstlane(CNT[e]);
    for (int i = chunk; i < n; i += ACT_NCHUNK) {
        const int p = __builtin_amdgcn_readfirstlane(LIST[e * 2048 + i]);
        const int t = p >> 1;
        const ushort* gurow = GU + (size_t)t * N1;
        const unsigned* xap = (const unsigned*)(gurow + 8192 + e * 32);
        float xg[16], xu[16];
#pragma unroll
        for (int r = 0; r < 8; r++) {
            unsigned w = xap[r];
            xg[2 * r] = lo2f(w); xg[2 * r + 1] = hi2f(w);
        }
#pragma unroll
        for (int r = 0; r < 8; r++) {
            unsigned w = xap[8 + r];
            xu[2 * r] = lo2f(w); xu[2 * r + 1] = hi2f(w);
        }
        const unsigned gw = *(const unsigned*)(gurow + f);
        const unsigned uw = *(const unsigned*)(gurow + 4096 + f);
        float lg0 = 0.f, lg1 = 0.f, lu0 = 0.f, lu1 = 0.f;
#pragma unroll
        for (int r = 0; r < 16; r++) {
            lg0 += xg[r] * bg[r].x;
            lg1 += xg[r] * bg[r].y;
            lu0 += xu[r] * bu[r].x;
            lu1 += xu[r] * bu[r].y;
        }
        const float gate0 = lo2f(gw) + LSCALE * lg0;
        const float gate1 = hi2f(gw) + LSCALE * lg1;
        const float up0 = lo2f(uw) + LSCALE * lu0;
        const float up1 = hi2f(uw) + LSCALE * lu1;
        const float a0 = (gate0 / (1.f + expf(-gate0))) * up0;
        const float a1 = (gate1 / (1.f + expf(-gate1))) * up1;
        ACT[((size_t)p * FDIM + f) >> 1] = (unsigned)f2u(a0) | ((unsigned)f2u(a1) << 16);
    }
}

// -------- Combine: split-K reduce (bf16 partials) + LoRA-down + wsum --------
__global__ __launch_bounds__(256) void combine2_kernel(
    const ushort* __restrict__ C2,   // [SPLITK2][2048][N2] bf16: DOWN | AD
    const float* __restrict__ b_down, const int* __restrict__ SEL,
    const float* __restrict__ WTS, float* __restrict__ out)
{
    const int t = blockIdx.x, tid = threadIdx.x;
    const int e0 = SEL[t * 2 + 0], e1 = SEL[t * 2 + 1];
    const float w0 = WTS[t * 2 + 0], w1 = WTS[t * 2 + 1];
    __shared__ float ad0[16], ad1[16];
    if (tid < 16) {
        float v = 0.f;
#pragma unroll
        for (int z = 0; z < SPLITK2; z++)
            v += u2f(C2[((size_t)z * 2048 + 2 * t) * N2 + 1024 + e0 * 16 + tid]);
        ad0[tid] = v;
    } else if (tid < 32) {
        float v = 0.f;
#pragma unroll
        for (int z = 0; z < SPLITK2; z++)
            v += u2f(C2[((size_t)z * 2048 + 2 * t + 1) * N2 + 1024 + e1 * 16 + (tid - 16)]);
        ad1[tid - 16] = v;
    }
    __syncthreads();
    const float* B0 = b_down + (size_t)e0 * RLORA * HDIM;
    const float* B1 = b_down + (size_t)e1 * RLORA * HDIM;
    for (int h = tid; h < HDIM; h += 256) {
        float v0 = 0.f, v1 = 0.f;
#pragma unroll
        for (int z = 0; z < SPLITK2; z++) {
            v0 += u2f(C2[((size_t)z * 2048 + 2 * t) * N2 + h]);
            v1 += u2f(C2[((size_t)z * 2048 + 2 * t + 1) * N2 + h]);
        }
        float l0 = 0.f, l1 = 0.f;
#pragma unroll
        for (int r = 0; r < 16; r++) {
            l0 += ad0[r] * B0[r * HDIM + h];
            l1 += ad1[r] * B1[r * HDIM + h];
        }
        out[(size_t)t * HDIM + h] = w0 * (v0 + LSCALE * l0) + w1 * (v1 + LSCALE * l1);
    }
}

extern "C" void kernel_launch(void* const* d_in, const int* in_sizes, int n_in,
                              void* d_out, int out_size, void* d_ws, size_t ws_size,
                              hipStream_t stream) {
    (void)in_sizes; (void)n_in; (void)out_size; (void)ws_size;
    const float* x       = (const float*)d_in[0];
    const float* noise   = (const float*)d_in[1];
    const float* w_route = (const float*)d_in[2];
    const float* w_noise = (const float*)d_in[3];
    const float* w_gate  = (const float*)d_in[4];
    const float* w_up    = (const float*)d_in[5];
    const float* w_down  = (const float*)d_in[6];
    const float* a_gate  = (const float*)d_in[7];
    const float* b_gate  = (const float*)d_in[8];
    const float* a_up    = (const float*)d_in[9];
    const float* b_up    = (const float*)d_in[10];
    const float* a_down  = (const float*)d_in[11];
    const float* b_down  = (const float*)d_in[12];
    float* out    = (float*)d_out;
    float* rl_out = out + (size_t)T_TOK * HDIM;

    char* ws = (char*)d_ws;
    // Union region: C1b [1024][8448] bf16 (16.5 MB, dead after act3) and
    // C2 [4][2048][1152] bf16 (18.9 MB, written by GEMM2 after act3). 19 MB.
    ushort* C1b  = (ushort*)(ws);
    ushort* C2   = (ushort*)(ws);
    ushort* WGUA = (ushort*)(ws + (size_t)(19 << 20));    // [8448][1024] bf16 = 16.5 MB
    bf16*   ACT  = (bf16*)(ws + (size_t)(36 << 20));      // [2048][4096] bf16 = 16 MB
    ushort* WDA  = (ushort*)(ws + (size_t)(52 << 20));    // [1152][4096] bf16 = 9 MB
    ushort* XB   = (ushort*)(ws + (size_t)(62 << 20));    // [1024][1024] bf16 = 2 MB
    int*    LIST = (int*)(ws + (size_t)(65 << 20));       // 64 KB
    int*    CNT  = (int*)(ws + (size_t)(65 << 20) + (1 << 17));
    int*    SEL  = (int*)(ws + (size_t)(65 << 20) + (1 << 17) + 4096);
    float*  WTS  = (float*)(ws + (size_t)(65 << 20) + (1 << 17) + 16384);

    router_kernel<<<T_TOK, 256, 0, stream>>>(x, noise, w_route, w_noise, rl_out, SEL, WTS);

    prep_kernel<<<13697, 256, 0, stream>>>(x, w_gate, w_up, w_down, a_gate, a_up, a_down,
                                           XB, WGUA, WDA, SEL, CNT, LIST);

    // GEMM1: C1b[1024][8448] = XB @ WGUA^T (bf16). grid 66*8=528 (%8==0), z=1
    gemm128<1><<<dim3((N1 / 128) * (T_TOK / 128), 1, 1), 256, 0, stream>>>(
        XB, WGUA, C1b, T_TOK, N1, HDIM, T_TOK / 128);

    act3_kernel<<<dim3(NEXP, FDIM / 512, ACT_NCHUNK), 256, 0, stream>>>(
        C1b, b_gate, b_up, CNT, LIST, (unsigned*)ACT);

    // GEMM2: C2[z][2048][1152] bf16 partials = ACT @ WDA^T. grid 144 (%8==0), z=4
    gemm128<SPLITK2><<<dim3((N2 / 128) * (2 * T_TOK / 128), 1, SPLITK2), 256, 0, stream>>>(
        (const ushort*)ACT, WDA, C2, 2 * T_TOK, N2, FDIM, 2 * T_TOK / 128);

    combine2_kernel<<<T_TOK, 256, 0, stream>>>(C2, b_down, SEL, WTS, out);
}

// Round 17
// 138.208 us; speedup vs baseline: 1.0798x; 1.0798x over previous
//
#include <hip/hip_runtime.h>
#include <hip/hip_bf16.h>

typedef __hip_bfloat16 bf16;
typedef __attribute__((ext_vector_type(4))) float f32x4;
typedef __attribute__((ext_vector_type(8))) __bf16 bf16x8;

#define T_TOK 1024
#define HDIM 1024
#define FDIM 4096
#define NEXP 8
#define RLORA 16
#define LSCALE 2.0f
#define N1 8448   // cols of fused GEMM1: 4096 gate + 4096 up + 256 XA
#define N2 1152   // cols of fused GEMM2: 1024 down + 128 AD
#define SPLITK2 4
#define ACT_NCHUNK 8

__device__ inline float b2f(bf16 v) { return __bfloat162float(v); }
__device__ inline bf16 f2b(float v) { return __float2bfloat16(v); }
__device__ inline ushort f2u(float v) { return __builtin_bit_cast(ushort, __float2bfloat16(v)); }
__device__ inline float u2f(ushort v) { return __bfloat162float(__builtin_bit_cast(bf16, v)); }
__device__ inline float lo2f(unsigned w) { return __builtin_bit_cast(float, w << 16); }
__device__ inline float hi2f(unsigned w) { return __builtin_bit_cast(float, w & 0xffff0000u); }

typedef const __attribute__((address_space(1))) unsigned int* gptr_t;
typedef __attribute__((address_space(3))) unsigned int* lptr_t;
__device__ __forceinline__ void glds16(const void* g, void* l) {
    __builtin_amdgcn_global_load_lds((gptr_t)g, (lptr_t)l, 16, 0, 0);
}

// ---------------- Router: logits, softmax, top2 -----------------------------
__global__ __launch_bounds__(256) void router_kernel(
    const float* __restrict__ x, const float* __restrict__ noise,
    const float* __restrict__ w_route, const float* __restrict__ w_noise,
    float* __restrict__ rl_out, int* __restrict__ SEL, float* __restrict__ WTS)
{
    const int t = blockIdx.x, tid = threadIdx.x;
    const float* xr = x + t * HDIM;
    float acc[16];
#pragma unroll
    for (int j = 0; j < 16; j++) acc[j] = 0.f;
    for (int h = tid; h < HDIM; h += 256) {
        float xv = xr[h];
        const float* wr = w_route + h * NEXP;
        const float* wn = w_noise + h * NEXP;
#pragma unroll
        for (int j = 0; j < 8; j++) acc[j] += xv * wr[j];
#pragma unroll
        for (int j = 0; j < 8; j++) acc[8 + j] += xv * wn[j];
    }
#pragma unroll
    for (int j = 0; j < 16; j++) {
        for (int off = 32; off > 0; off >>= 1) acc[j] += __shfl_down(acc[j], off, 64);
    }
    __shared__ float red[4][16];
    const int wave = tid >> 6, lane = tid & 63;
    if (lane == 0) {
#pragma unroll
        for (int j = 0; j < 16; j++) red[wave][j] = acc[j];
    }
    __syncthreads();
    if (tid == 0) {
        float rl[8];
#pragma unroll
        for (int j = 0; j < 8; j++) {
            float lg = red[0][j] + red[1][j] + red[2][j] + red[3][j];
            float nl = red[0][8 + j] + red[1][8 + j] + red[2][8 + j] + red[3][8 + j];
            float sp = fmaxf(nl, 0.f) + log1pf(expf(-fabsf(nl)));
            rl[j] = lg + noise[t * NEXP + j] * sp;
            rl_out[t * NEXP + j] = rl[j];
        }
        float m = rl[0];
#pragma unroll
        for (int j = 1; j < 8; j++) m = fmaxf(m, rl[j]);
        float p[8];
#pragma unroll
        for (int j = 0; j < 8; j++) p[j] = expf(rl[j] - m);
        int i1 = 0;
#pragma unroll
        for (int j = 1; j < 8; j++) if (p[j] > p[i1]) i1 = j;
        int i2 = (i1 == 0) ? 1 : 0;
#pragma unroll
        for (int j = 0; j < 8; j++) { if (j != i1 && p[j] > p[i2]) i2 = j; }
        float w1 = p[i1] / (p[i1] + p[i2]);
        float w2 = p[i2] / (p[i1] + p[i2]);
        SEL[t * 2 + 0] = i1; SEL[t * 2 + 1] = i2;
        WTS[t * 2 + 0] = w1; WTS[t * 2 + 1] = w2;
    }
}

// ---------------- Fused prep: transposes + LoRA packs + x convert + lists ---
__device__ __forceinline__ void transpose_tile(
    const float* __restrict__ in, ushort* __restrict__ out,
    int rows, int cols, int bx, int by, int tid)
{
    __shared__ float tile[32][33];
    const int tx = tid & 31, ty = tid >> 5;
#pragma unroll
    for (int i = 0; i < 32; i += 8)
        tile[ty + i][tx] = in[(size_t)(by + ty + i) * cols + bx + tx];
    __syncthreads();
#pragma unroll
    for (int i = 0; i < 32; i += 8)
        out[(size_t)(bx + ty + i) * rows + by + tx] = f2u(tile[tx][ty + i]);
}

__global__ __launch_bounds__(256) void prep_kernel(
    const float* __restrict__ x,
    const float* __restrict__ w_gate, const float* __restrict__ w_up,
    const float* __restrict__ w_down,
    const float* __restrict__ a_gate, const float* __restrict__ a_up,
    const float* __restrict__ a_down,
    ushort* __restrict__ XB, ushort* __restrict__ WGUA, ushort* __restrict__ WDA,
    const int* __restrict__ SEL, int* __restrict__ CNT, int* __restrict__ LIST)
{
    const int bid = blockIdx.x, tid = threadIdx.x;
    if (bid < 4096) {
        transpose_tile(w_gate, WGUA, HDIM, FDIM, (bid & 127) * 32, (bid >> 7) * 32, tid);
    } else if (bid < 8192) {
        const int s = bid - 4096;
        transpose_tile(w_up, WGUA + (size_t)4096 * HDIM, HDIM, FDIM, (s & 127) * 32, (s >> 7) * 32, tid);
    } else if (bid < 12288) {
        const int s = bid - 8192;
        transpose_tile(w_down, WDA, FDIM, HDIM, (s & 31) * 32, (s >> 5) * 32, tid);
    } else if (bid < 12544) {
        const int row = bid - 12288;  // 0..255: e*32 + mat*16 + r
        const int e = row >> 5, mat = (row >> 4) & 1, r = row & 15;
        const float* src = (mat ? a_up : a_gate) + (size_t)e * HDIM * RLORA;
        ushort* dst = WGUA + (size_t)(8192 + row) * HDIM;
        for (int h = tid; h < HDIM; h += 256) dst[h] = f2u(src[h * RLORA + r]);
    } else if (bid < 12672) {
        const int row = bid - 12544;  // 0..127: e*16 + r
        const int e = row >> 4, r = row & 15;
        const float* src = a_down + (size_t)e * FDIM * RLORA;
        ushort* dst = WDA + (size_t)(1024 + row) * FDIM;
        for (int f = tid; f < FDIM; f += 256) dst[f] = f2u(src[f * RLORA + r]);
    } else if (bid < 13696) {
        const int i = (bid - 12672) * 256 + tid;
        const float4 v = *reinterpret_cast<const float4*>(x + (size_t)i * 4);
        ushort4 o;
        o.x = f2u(v.x); o.y = f2u(v.y); o.z = f2u(v.z); o.w = f2u(v.w);
        *reinterpret_cast<ushort4*>(XB + (size_t)i * 4) = o;
    } else {
        // expert list build (single block, LDS counters — no global memset)
        __shared__ int cnt[NEXP];
        if (tid < NEXP) cnt[tid] = 0;
        __syncthreads();
        for (int p = tid; p < 2 * T_TOK; p += 256) {
            const int e = SEL[p];
            const int idx = atomicAdd(&cnt[e], 1);
            LIST[e * 2048 + idx] = p;
        }
        __syncthreads();
        if (tid < NEXP) CNT[tid] = cnt[tid];
    }
}

// ---- MFMA GEMM: 128x128, BK=64, glds + XOR swizzle, single 32KB buffer -----
// r6-verified race-free loop: STAGE -> __syncthreads -> compute -> __syncthreads.
// Session-final structure: counted-vmcnt pipelining raced twice (r10/r12) and
// BK=128 phase-amortization regressed (r16, occupancy loss — m132 replay).
template <int SPLITK>
__global__ __launch_bounds__(256) void gemm128(
    const ushort* __restrict__ A, const ushort* __restrict__ Bt,
    ushort* __restrict__ C, int M, int N, int Kd, int ny)
{
    __shared__ __align__(16) ushort sA[128 * 64];
    __shared__ __align__(16) ushort sB[128 * 64];
    const int nwg = gridDim.x;
    const int q = nwg >> 3;  // nwg % 8 == 0 required
    const int wg = (blockIdx.x & 7) * q + (blockIdx.x >> 3);
    const int bn0 = (wg / ny) * 128, bm0 = (wg % ny) * 128;

    const int tid = threadIdx.x;
    const int wave = tid >> 6, lane = tid & 63;
    const int wm = wave >> 1, wn = wave & 1;

    f32x4 acc[4][4];
#pragma unroll
    for (int m = 0; m < 4; m++)
#pragma unroll
        for (int n = 0; n < 4; n++) acc[m][n] = (f32x4){0.f, 0.f, 0.f, 0.f};

    const int srow = tid >> 3;                       // 0..31 per pass
    const int sgrp8 = ((tid & 7) ^ (srow & 7)) * 8;  // pre-swizzled col (elems)

    const int kchunk = Kd / SPLITK;
    const int kbeg = blockIdx.z * kchunk, kend = kbeg + kchunk;

    for (int k0 = kbeg; k0 < kend; k0 += 64) {
#pragma unroll
        for (int i = 0; i < 4; i++) {
            const int row = i * 32 + srow;
            glds16(A + (size_t)(bm0 + row) * Kd + k0 + sgrp8, &sA[i * 2048 + wave * 512]);
            glds16(Bt + (size_t)(bn0 + row) * Kd + k0 + sgrp8, &sB[i * 2048 + wave * 512]);
        }
        __syncthreads();  // drains vmcnt -> tile complete (verified-safe r6)
#pragma unroll
        for (int kk = 0; kk < 2; kk++) {
            bf16x8 af[4], bfr[4];
            const int colb = (kk * 32 + (lane >> 4) * 8) * 2;
#pragma unroll
            for (int m = 0; m < 4; m++) {
                const int row = wm * 64 + m * 16 + (lane & 15);
                af[m] = *reinterpret_cast<const bf16x8*>(
                    (const char*)sA + row * 128 + (colb ^ ((row & 7) << 4)));
            }
#pragma unroll
            for (int n = 0; n < 4; n++) {
                const int row = wn * 64 + n * 16 + (lane & 15);
                bfr[n] = *reinterpret_cast<const bf16x8*>(
                    (const char*)sB + row * 128 + (colb ^ ((row & 7) << 4)));
            }
#pragma unroll
            for (int m = 0; m < 4; m++)
#pragma unroll
                for (int n = 0; n < 4; n++)
                    acc[m][n] = __builtin_amdgcn_mfma_f32_16x16x32_bf16(af[m], bfr[n], acc[m][n], 0, 0, 0);
        }
        __syncthreads();  // all waves done reading before next overwrite
    }

    const size_t zoff = (size_t)blockIdx.z * M * N;
    const int rg = lane & 15, qg = lane >> 4;
#pragma unroll
    for (int m = 0; m < 4; m++) {
#pragma unroll
        for (int n = 0; n < 4; n++) {
            const int row0 = bm0 + wm * 64 + m * 16 + qg * 4;
            const int col = bn0 + wn * 64 + n * 16 + rg;
#pragma unroll
            for (int j = 0; j < 4; j++)
                C[zoff + (size_t)(row0 + j) * N + col] = f2u(acc[m][n][j]);
        }
    }
}

// -------- Expert-grouped LoRA gate/up + SiLU -> ACT, B in registers ---------
__global__ __launch_bounds__(256) void act3_kernel(
    const ushort* __restrict__ GU,   // [T, N1] bf16: G | U | XA
    const float* __restrict__ b_gate, const float* __restrict__ b_up,
    const int* __restrict__ CNT, const int* __restrict__ LIST,
    unsigned* __restrict__ ACT)      // [2048, FDIM/2] packed 2xbf16
{
    const int e = blockIdx.x, chunk = blockIdx.z;
    const int tid = threadIdx.x;
    const int f = blockIdx.y * 512 + tid * 2;

    float2 bg[16], bu[16];
    {
        const float* bgp = b_gate + (size_t)e * RLORA * FDIM + f;
        const float* bup = b_up + (size_t)e * RLORA * FDIM + f;
#pragma unroll
        for (int r = 0; r < 16; r++) {
            bg[r] = *reinterpret_cast<const float2*>(bgp + (size_t)r * FDIM);
            bu[r] = *reinterpret_cast<const float2*>(bup + (size_t)r * FDIM);
        }
    }

    const int n = __builtin_amdgcn_readfirstlane(CNT[e]);
    for (int i = chunk; i < n; i += ACT_NCHUNK) {
        const int p = __builtin_amdgcn_readfirstlane(LIST[e * 2048 + i]);
        const int t = p >> 1;
        const ushort* gurow = GU + (size_t)t * N1;
        const unsigned* xap = (const unsigned*)(gurow + 8192 + e * 32);
        float xg[16], xu[16];
#pragma unroll
        for (int r = 0; r < 8; r++) {
            unsigned w = xap[r];
            xg[2 * r] = lo2f(w); xg[2 * r + 1] = hi2f(w);
        }
#pragma unroll
        for (int r = 0; r < 8; r++) {
            unsigned w = xap[8 + r];
            xu[2 * r] = lo2f(w); xu[2 * r + 1] = hi2f(w);
        }
        const unsigned gw = *(const unsigned*)(gurow + f);
        const unsigned uw = *(const unsigned*)(gurow + 4096 + f);
        float lg0 = 0.f, lg1 = 0.f, lu0 = 0.f, lu1 = 0.f;
#pragma unroll
        for (int r = 0; r < 16; r++) {
            lg0 += xg[r] * bg[r].x;
            lg1 += xg[r] * bg[r].y;
            lu0 += xu[r] * bu[r].x;
            lu1 += xu[r] * bu[r].y;
        }
        const float gate0 = lo2f(gw) + LSCALE * lg0;
        const float gate1 = hi2f(gw) + LSCALE * lg1;
        const float up0 = lo2f(uw) + LSCALE * lu0;
        const float up1 = hi2f(uw) + LSCALE * lu1;
        const float a0 = (gate0 / (1.f + expf(-gate0))) * up0;
        const float a1 = (gate1 / (1.f + expf(-gate1))) * up1;
        ACT[((size_t)p * FDIM + f) >> 1] = (unsigned)f2u(a0) | ((unsigned)f2u(a1) << 16);
    }
}

// -------- Combine: split-K reduce (bf16 partials) + LoRA-down + wsum --------
__global__ __launch_bounds__(256) void combine2_kernel(
    const ushort* __restrict__ C2,   // [SPLITK2][2048][N2] bf16: DOWN | AD
    const float* __restrict__ b_down, const int* __restrict__ SEL,
    const float* __restrict__ WTS, float* __restrict__ out)
{
    const int t = blockIdx.x, tid = threadIdx.x;
    const int e0 = SEL[t * 2 + 0], e1 = SEL[t * 2 + 1];
    const float w0 = WTS[t * 2 + 0], w1 = WTS[t * 2 + 1];
    __shared__ float ad0[16], ad1[16];
    if (tid < 16) {
        float v = 0.f;
#pragma unroll
        for (int z = 0; z < SPLITK2; z++)
            v += u2f(C2[((size_t)z * 2048 + 2 * t) * N2 + 1024 + e0 * 16 + tid]);
        ad0[tid] = v;
    } else if (tid < 32) {
        float v = 0.f;
#pragma unroll
        for (int z = 0; z < SPLITK2; z++)
            v += u2f(C2[((size_t)z * 2048 + 2 * t + 1) * N2 + 1024 + e1 * 16 + (tid - 16)]);
        ad1[tid - 16] = v;
    }
    __syncthreads();
    const float* B0 = b_down + (size_t)e0 * RLORA * HDIM;
    const float* B1 = b_down + (size_t)e1 * RLORA * HDIM;
    for (int h = tid; h < HDIM; h += 256) {
        float v0 = 0.f, v1 = 0.f;
#pragma unroll
        for (int z = 0; z < SPLITK2; z++) {
            v0 += u2f(C2[((size_t)z * 2048 + 2 * t) * N2 + h]);
            v1 += u2f(C2[((size_t)z * 2048 + 2 * t + 1) * N2 + h]);
        }
        float l0 = 0.f, l1 = 0.f;
#pragma unroll
        for (int r = 0; r < 16; r++) {
            l0 += ad0[r] * B0[r * HDIM + h];
            l1 += ad1[r] * B1[r * HDIM + h];
        }
        out[(size_t)t * HDIM + h] = w0 * (v0 + LSCALE * l0) + w1 * (v1 + LSCALE * l1);
    }
}

extern "C" void kernel_launch(void* const* d_in, const int* in_sizes, int n_in,
                              void* d_out, int out_size, void* d_ws, size_t ws_size,
                              hipStream_t stream) {
    (void)in_sizes; (void)n_in; (void)out_size; (void)ws_size;
    const float* x       = (const float*)d_in[0];
    const float* noise   = (const float*)d_in[1];
    const float* w_route = (const float*)d_in[2];
    const float* w_noise = (const float*)d_in[3];
    const float* w_gate  = (const float*)d_in[4];
    const float* w_up    = (const float*)d_in[5];
    const float* w_down  = (const float*)d_in[6];
    const float* a_gate  = (const float*)d_in[7];
    const float* b_gate  = (const float*)d_in[8];
    const float* a_up    = (const float*)d_in[9];
    const float* b_up    = (const float*)d_in[10];
    const float* a_down  = (const float*)d_in[11];
    const float* b_down  = (const float*)d_in[12];
    float* out    = (float*)d_out;
    float* rl_out = out + (size_t)T_TOK * HDIM;

    char* ws = (char*)d_ws;
    // Union region: C1b [1024][8448] bf16 (16.5 MB, dead after act3) and
    // C2 [4][2048][1152] bf16 (18.9 MB, written by GEMM2 after act3). 19 MB.
    ushort* C1b  = (ushort*)(ws);
    ushort* C2   = (ushort*)(ws);
    ushort* WGUA = (ushort*)(ws + (size_t)(19 << 20));    // [8448][1024] bf16 = 16.5 MB
    bf16*   ACT  = (bf16*)(ws + (size_t)(36 << 20));      // [2048][4096] bf16 = 16 MB
    ushort* WDA  = (ushort*)(ws + (size_t)(52 << 20));    // [1152][4096] bf16 = 9 MB
    ushort* XB   = (ushort*)(ws + (size_t)(62 << 20));    // [1024][1024] bf16 = 2 MB
    int*    LIST = (int*)(ws + (size_t)(65 << 20));       // 64 KB
    int*    CNT  = (int*)(ws + (size_t)(65 << 20) + (1 << 17));
    int*    SEL  = (int*)(ws + (size_t)(65 << 20) + (1 << 17) + 4096);
    float*  WTS  = (float*)(ws + (size_t)(65 << 20) + (1 << 17) + 16384);

    router_kernel<<<T_TOK, 256, 0, stream>>>(x, noise, w_route, w_noise, rl_out, SEL, WTS);

    prep_kernel<<<13697, 256, 0, stream>>>(x, w_gate, w_up, w_down, a_gate, a_up, a_down,
                                           XB, WGUA, WDA, SEL, CNT, LIST);

    // GEMM1: C1b[1024][8448] = XB @ WGUA^T (bf16). grid 66*8=528 (%8==0), z=1
    gemm128<1><<<dim3((N1 / 128) * (T_TOK / 128), 1, 1), 256, 0, stream>>>(
        XB, WGUA, C1b, T_TOK, N1, HDIM, T_TOK / 128);

    act3_kernel<<<dim3(NEXP, FDIM / 512, ACT_NCHUNK), 256, 0, stream>>>(
        C1b, b_gate, b_up, CNT, LIST, (unsigned*)ACT);

    // GEMM2: C2[z][2048][1152] bf16 partials = ACT @ WDA^T. grid 144 (%8==0), z=4
    gemm128<SPLITK2><<<dim3((N2 / 128) * (2 * T_TOK / 128), 1, SPLITK2), 256, 0, stream>>>(
        (const ushort*)ACT, WDA, C2, 2 * T_TOK, N2, FDIM, 2 * T_TOK / 128);

    combine2_kernel<<<T_TOK, 256, 0, stream>>>(C2, b_down, SEL, WTS, out);
}